// Round 8
// baseline (132.697 us; speedup 1.0000x reference)
//
#include <hip/hip_runtime.h>

// E3Hamiltonian spin projection: fixed 4x4 complex mix over channel dim.
// [B=65536, C=8, nL*nR=169] f32, channels [r0 r1 r2 r3 | i0 i1 i2 i3].
//
// Round-8: zero-LDS single-phase streaming, iterated over OUTPUT quads so
// every store is 16B-aligned (out offset = 4q, item stride 1352 % 4 == 0).
// Loads are 4B-aligned float4 (cheap: wave-contiguous request set); each
// input element is read twice but the second read hits L1/L3 (reuse distance
// <= ~127 quads ~ one block). Butterfly per out-channel c:
//   out[c] = x*ca + y*cb,  x = in[A(c)], y = in[B(c)]
//   A = {0,3,3,0,4,1,1,4}, B = {2,5,5,2,6,7,7,6}
//   ca = -s only for c=5 (mask 0x20); cb = -s for c in {2,3,7} (mask 0x8C).
// Quads straddling a channel-plane boundary (~6/338) use per-element loads;
// their store stays aligned.

#define PLANE 169
#define CSTRIDE 1352          // floats per item
#define QPI 338               // output quads per item

typedef float f4u __attribute__((ext_vector_type(4), aligned(4)));

__device__ __forceinline__ float mix_one(const float* __restrict__ ib,
                                         int c, int j) {
    const int A = (0x41140330u >> (c * 4)) & 0xF;
    const int B = (0x67762552u >> (c * 4)) & 0xF;
    const unsigned ca_bits = 0x3F3504F3u | (((0x20u >> c) & 1u) << 31);
    const unsigned cb_bits = 0x3F3504F3u | (((0x8Cu >> c) & 1u) << 31);
    float v = ib[A * PLANE + j] * __builtin_bit_cast(float, ca_bits);
    return fmaf(ib[B * PLANE + j], __builtin_bit_cast(float, cb_bits), v);
}

__global__ __launch_bounds__(256) void spin_proj_kernel(
    const float* __restrict__ in, float* __restrict__ out, int total) {
    int t = blockIdx.x * 256 + threadIdx.x;
    if (t >= total) return;

    const int n = t / QPI;                 // item (magic-mul div)
    const int q = t - n * QPI;             // output quad within item
    const int idx0 = 4 * q;
    const int c0 = idx0 / PLANE;           // output channel of first element
    const int j0 = idx0 - c0 * PLANE;

    const float* __restrict__ ib = in + (size_t)n * CSTRIDE;
    float4 o;

    if (j0 <= PLANE - 4) {
        // Whole quad inside channel c0: two 4B-aligned float4 loads.
        const int A = (0x41140330u >> (c0 * 4)) & 0xF;
        const int B = (0x67762552u >> (c0 * 4)) & 0xF;
        const unsigned ca_bits = 0x3F3504F3u | (((0x20u >> c0) & 1u) << 31);
        const unsigned cb_bits = 0x3F3504F3u | (((0x8Cu >> c0) & 1u) << 31);
        const float ca = __builtin_bit_cast(float, ca_bits);
        const float cb = __builtin_bit_cast(float, cb_bits);
        f4u x = *(const f4u*)(ib + A * PLANE + j0);
        f4u y = *(const f4u*)(ib + B * PLANE + j0);
        o.x = fmaf(y.x, cb, x.x * ca);
        o.y = fmaf(y.y, cb, x.y * ca);
        o.z = fmaf(y.z, cb, x.z * ca);
        o.w = fmaf(y.w, cb, x.w * ca);
    } else {
        // Straddles channel boundary: per-element channel + scalar loads.
        int cA = c0,     jA = j0;
        int cB = c0,     jB = j0 + 1;
        int cC = c0,     jC = j0 + 2;
        int cD = c0,     jD = j0 + 3;
        if (jB >= PLANE) { cB++; jB -= PLANE; }
        if (jC >= PLANE) { cC++; jC -= PLANE; }
        if (jD >= PLANE) { cD++; jD -= PLANE; }
        o.x = mix_one(ib, cA, jA);
        o.y = mix_one(ib, cB, jB);
        o.z = mix_one(ib, cC, jC);
        o.w = mix_one(ib, cD, jD);
    }

    // Store: 16B-aligned, coalesced across lanes.
    *(float4*)(out + (size_t)n * CSTRIDE + idx0) = o;
}

extern "C" void kernel_launch(void* const* d_in, const int* in_sizes, int n_in,
                              void* d_out, int out_size, void* d_ws, size_t ws_size,
                              hipStream_t stream) {
    const float* in = (const float*)d_in[0];
    float* out = (float*)d_out;

    const int n_items = in_sizes[0] / CSTRIDE;   // 65536
    const int total = n_items * QPI;             // 22,151,168 output quads
    const int grid = (total + 255) / 256;
    spin_proj_kernel<<<grid, 256, 0, stream>>>(in, out, total);
}